// Round 12
// baseline (202.313 us; speedup 1.0000x reference)
//
#include <hip/hip_runtime.h>
#include <math.h>

#define NN 1024
#define WW 128
#define DD 1024
#define FF (NN * WW + NN)      // 132096 = 516*256
#define NROW (NN * WW)         // 131072
#define NCHUNK 516             // 256-float chunks per mask row
#define GWAVES 8192            // 2048 blocks * 4 waves

// ws layout: [feat: FF floats][f1: NROW floats][partial: NN*NCHUNK floats]
#define WS_F1_OFF   528384
#define WS_PART_OFF (WS_F1_OFF + (size_t)NROW * 4)          // 1052672
#define WS_NEEDED   (WS_PART_OFF + (size_t)NN * NCHUNK * 4) // 3166208

typedef float f32x4 __attribute__((ext_vector_type(4)));

__device__ __forceinline__ f32x4 nt4(const float* p) {
    return __builtin_nontemporal_load(reinterpret_cast<const f32x4*>(p));
}
__device__ __forceinline__ float wred(float s) {
    #pragma unroll
    for (int m = 32; m > 0; m >>= 1) s += __shfl_xor(s, m, 64);
    return s;
}
__device__ __forceinline__ float hred(float s) {   // reduce within each 32-lane half
    #pragma unroll
    for (int m = 16; m > 0; m >>= 1) s += __shfl_xor(s, m, 64);
    return s;
}

// ---------------- K1: f1 = relu(W1 @ x + b1), single coherent front (R7-proven) ----------------
__global__ __launch_bounds__(256) void w1dot(
    const float* __restrict__ x, const float* __restrict__ W1,
    const float* __restrict__ b1, float* __restrict__ f1)
{
    const int tid = threadIdx.x, lane = tid & 63;
    const int gw = blockIdx.x * 4 + (tid >> 6);   // 0..8191
    const f32x4 xv0 = *reinterpret_cast<const f32x4*>(x +   0 + lane * 4);
    const f32x4 xv1 = *reinterpret_cast<const f32x4*>(x + 256 + lane * 4);
    const f32x4 xv2 = *reinterpret_cast<const f32x4*>(x + 512 + lane * 4);
    const f32x4 xv3 = *reinterpret_cast<const f32x4*>(x + 768 + lane * 4);
    #pragma unroll
    for (int i = 0; i < 8; ++i) {
        const int r = (i * GWAVES + gw) * 2;      // rows r, r+1; grid covers 64MB/iter
        const float* rp = W1 + (size_t)r * DD + lane * 4;
        f32x4 a0 = nt4(rp) * xv0;
        f32x4 a1 = nt4(rp + DD) * xv0;
        a0 += nt4(rp + 256) * xv1;
        a1 += nt4(rp + DD + 256) * xv1;
        a0 += nt4(rp + 512) * xv2;
        a1 += nt4(rp + DD + 512) * xv2;
        a0 += nt4(rp + 768) * xv3;
        a1 += nt4(rp + DD + 768) * xv3;
        float s0 = wred((a0[0] + a0[1]) + (a0[2] + a0[3]));
        float s1 = wred((a1[0] + a1[1]) + (a1[2] + a1[3]));
        if (lane == 0) {
            const float v0 = s0 + b1[r];
            const float v1 = s1 + b1[r + 1];
            f1[r]     = v0 > 0.f ? v0 : 0.f;
            f1[r + 1] = v1 > 0.f ? v1 : 0.f;
        }
    }
}

// ---------------- K2: f2 = relu(W2 @ f1 + b2) -> feat, single coherent front ----------------
__global__ __launch_bounds__(256) void w2dot(
    const float* __restrict__ W2, const float* __restrict__ b2,
    const float* __restrict__ f1, const float* __restrict__ hidden,
    float* __restrict__ feat)
{
    const int tid = threadIdx.x, lane = tid & 63;
    const int gw = blockIdx.x * 4 + (tid >> 6);
    const int gtid = blockIdx.x * 256 + tid;
    if (gtid < NN) feat[NROW + gtid] = hidden[gtid];  // hidden tail
    #pragma unroll
    for (int i = 0; i < 8; ++i) {
        const int p  = i * GWAVES + gw;           // row-pair index, 0..65535
        const int rr = p * 2;                     // rows rr, rr+1 (same column n)
        const int n  = p >> 6;
        const f32x4 wv = nt4(W2 + (size_t)p * 256 + lane * 4);
        const f32x4 fv = *reinterpret_cast<const f32x4*>(f1 + (n << 7) + ((lane & 31) << 2));
        const f32x4 m = wv * fv;
        const float s = hred((m[0] + m[1]) + (m[2] + m[3]));
        if (lane == 0) {
            const float v = s + b2[rr];
            feat[rr] = v > 0.f ? v : 0.f;
        } else if (lane == 32) {
            const float v = s + b2[rr + 1];
            feat[rr + 1] = v > 0.f ? v : 0.f;
        }
    }
}

// ---------------- K3: coherent mask sweep + inline sparse gather -> per-chunk partials ----------------
// Unroll 8: compiler hoists 8 independent nt4 mask loads ahead of the
// ballot/gather bodies -> ~8 x 16B in flight per wave (was ~2).
__global__ __launch_bounds__(256) void scangather(
    const float* __restrict__ mask, const float* __restrict__ Wi,
    const float* __restrict__ feat, float* __restrict__ partial)
{
    const int tid = threadIdx.x, lane = tid & 63, w = tid >> 6;
    const int wave_id = blockIdx.x * 4 + w;
    #pragma unroll 8
    for (int c = wave_id; c < NN * NCHUNK; c += GWAVES) {
        const f32x4 m = nt4(mask + (size_t)c * 256 + lane * 4);
        float a = 0.f;
        if ((m[0] != 0.f) || (m[1] != 0.f) || (m[2] != 0.f) || (m[3] != 0.f)) {
            const int n  = c / NCHUNK;
            const int fl = (c - n * NCHUNK) * 256 + lane * 4;
            const float* wrow = Wi + (size_t)n * FF;
            if (m[0] != 0.f) a += wrow[fl]     * feat[fl];
            if (m[1] != 0.f) a += wrow[fl + 1] * feat[fl + 1];
            if (m[2] != 0.f) a += wrow[fl + 2] * feat[fl + 2];
            if (m[3] != 0.f) a += wrow[fl + 3] * feat[fl + 3];
        }
        const float s = wred(a);
        if (lane == 0) partial[c] = s;
    }
}

// ---------------- K4: per-row sum of partials + tanh + h ----------------
__global__ __launch_bounds__(256) void sumk(
    const float* __restrict__ partial, const float* __restrict__ bi,
    const float* __restrict__ hidden, float* __restrict__ out)
{
    const int n = blockIdx.x, tid = threadIdx.x;
    const float* prow = partial + (size_t)n * NCHUNK;
    float acc = 0.f;
    for (int j = tid; j < NCHUNK; j += 256) acc += prow[j];
    acc = wred(acc);
    __shared__ float p4[4];
    if ((tid & 63) == 0) p4[tid >> 6] = acc;
    __syncthreads();
    if (tid == 0) {
        const float s = (p4[0] + p4[1]) + (p4[2] + p4[3]);
        out[1 + n] = hidden[n] + tanhf(s + bi[n]);
    }
}

// ---------------- K5: y = sum(pred * h) ----------------
__global__ __launch_bounds__(256) void predk(
    const float* __restrict__ pred, const float* __restrict__ h,
    float* __restrict__ out)
{
    const int tid = threadIdx.x;
    float acc = 0.f;
    for (int i = tid; i < NN; i += 256) acc += pred[i] * h[i];
    acc = wred(acc);
    __shared__ float p4[4];
    if ((tid & 63) == 0) p4[tid >> 6] = acc;
    __syncthreads();
    if (tid == 0) out[0] = (p4[0] + p4[1]) + (p4[2] + p4[3]);
}

// ---------------- minimal fallback if ws too small ----------------
__global__ __launch_bounds__(256) void feat_kernel(
    const float* __restrict__ x, const float* __restrict__ hidden,
    const float* __restrict__ W1, const float* __restrict__ b1,
    const float* __restrict__ W2, const float* __restrict__ b2,
    float* __restrict__ feat)
{
    const int n = blockIdx.x, tid = threadIdx.x, lane = tid & 63, wave = tid >> 6;
    __shared__ float x_s[DD];
    __shared__ float f1_s[WW];
    *reinterpret_cast<float4*>(x_s + tid * 4) = *reinterpret_cast<const float4*>(x + tid * 4);
    if (tid == 0) feat[NROW + n] = hidden[n];
    __syncthreads();
    const float* W1n = W1 + (size_t)n * WW * DD;
    for (int r = wave * 32; r < wave * 32 + 32; ++r) {
        const float* row = W1n + (size_t)r * DD;
        float4 acc = {0.f, 0.f, 0.f, 0.f};
        #pragma unroll
        for (int it = 0; it < 4; ++it) {
            const float4 a  = *reinterpret_cast<const float4*>(row + it * 256 + lane * 4);
            const float4 xv = *reinterpret_cast<const float4*>(x_s + it * 256 + lane * 4);
            acc.x += a.x * xv.x; acc.y += a.y * xv.y;
            acc.z += a.z * xv.z; acc.w += a.w * xv.w;
        }
        float s = wred((acc.x + acc.y) + (acc.z + acc.w));
        if (lane == 0) {
            float v = s + b1[n * WW + r];
            f1_s[r] = v > 0.f ? v : 0.f;
        }
    }
    __syncthreads();
    const float* W2n = W2 + (size_t)n * WW * WW;
    for (int r = wave * 32; r < wave * 32 + 32; ++r) {
        const float2 a = *reinterpret_cast<const float2*>(W2n + (size_t)r * WW + lane * 2);
        const float2 f = *reinterpret_cast<const float2*>(f1_s + lane * 2);
        float s = wred(a.x * f.x + a.y * f.y);
        if (lane == 0) {
            float v = s + b2[n * WW + r];
            feat[n * WW + r] = v > 0.f ? v : 0.f;
        }
    }
}

__global__ __launch_bounds__(256) void sparse_kernel(
    const float* __restrict__ Wi, const float* __restrict__ mask,
    const float* __restrict__ bi, const float* __restrict__ hidden,
    const float* __restrict__ feat, float* __restrict__ out)
{
    const int n = blockIdx.x, tid = threadIdx.x;
    const float* mrow = mask + (size_t)n * FF;
    const float* wrow = Wi   + (size_t)n * FF;
    float acc = 0.f;
    for (int it = 0; it < FF / 1024; ++it) {
        const int f = it * 1024 + tid * 4;
        const float4 m = *reinterpret_cast<const float4*>(mrow + f);
        if (m.x != 0.f) acc += wrow[f + 0] * m.x * feat[f + 0];
        if (m.y != 0.f) acc += wrow[f + 1] * m.y * feat[f + 1];
        if (m.z != 0.f) acc += wrow[f + 2] * m.z * feat[f + 2];
        if (m.w != 0.f) acc += wrow[f + 3] * m.w * feat[f + 3];
    }
    acc = wred(acc);
    __shared__ float p4[4];
    if ((tid & 63) == 0) p4[tid >> 6] = acc;
    __syncthreads();
    if (tid == 0) {
        const float s = (p4[0] + p4[1]) + (p4[2] + p4[3]);
        out[1 + n] = hidden[n] + tanhf(s + bi[n]);
    }
}

extern "C" void kernel_launch(void* const* d_in, const int* in_sizes, int n_in,
                              void* d_out, int out_size, void* d_ws, size_t ws_size,
                              hipStream_t stream) {
    const float* x      = (const float*)d_in[0];
    const float* hidden = (const float*)d_in[1];
    const float* W1     = (const float*)d_in[2];
    const float* b1     = (const float*)d_in[3];
    const float* W2     = (const float*)d_in[4];
    const float* b2     = (const float*)d_in[5];
    const float* Wi     = (const float*)d_in[6];
    const float* bi     = (const float*)d_in[7];
    const float* mask   = (const float*)d_in[8];
    const float* pred   = (const float*)d_in[9];

    float* out     = (float*)d_out;
    float* feat    = (float*)d_ws;
    float* f1      = (float*)((char*)d_ws + WS_F1_OFF);
    float* partial = (float*)((char*)d_ws + WS_PART_OFF);

    if (ws_size >= WS_NEEDED) {
        w1dot<<<2048, 256, 0, stream>>>(x, W1, b1, f1);
        w2dot<<<2048, 256, 0, stream>>>(W2, b2, f1, hidden, feat);
        scangather<<<2048, 256, 0, stream>>>(mask, Wi, feat, partial);
        sumk<<<NN, 256, 0, stream>>>(partial, bi, hidden, out);
    } else {
        feat_kernel<<<NN, 256, 0, stream>>>(x, hidden, W1, b1, W2, b2, feat);
        sparse_kernel<<<NN, 256, 0, stream>>>(Wi, mask, bi, hidden, feat, out);
    }
    predk<<<1, 256, 0, stream>>>(pred, out + 1, out);
}